// Round 1
// baseline (270.663 us; speedup 1.0000x reference)
//
#include <hip/hip_runtime.h>
#include <cstdint>
#include <cstddef>

typedef __attribute__((ext_vector_type(4))) float f32x4;
typedef __bf16 bf16x8 __attribute__((ext_vector_type(8)));
typedef __attribute__((ext_vector_type(4))) unsigned int u32x4;
typedef __attribute__((ext_vector_type(2))) unsigned int u32x2;

#define DEVI __device__ __forceinline__

static constexpr int NB = 4;      // batches
static constexpr int NPTS = 8192; // N query points
static constexpr int SPTS = 2048; // S source points
static constexpr int DF = 256;    // feature dim of points1/points2
static constexpr int CIN = 512;   // concat width = 2*DF = K of GEMM1
static constexpr int MTOT = NB * NPTS; // 32768 rows

DEVI unsigned short f2b(float f) {
  union { float f; unsigned u; } v; v.f = f;
  unsigned r = v.u + 0x7FFFu + ((v.u >> 16) & 1u);
  return (unsigned short)(r >> 16);
}
DEVI float b2f(unsigned short h) {
  union { unsigned u; float f; } v; v.u = ((unsigned)h) << 16;
  return v.f;
}

// ---------------- BN param folding: scale = g*rsqrt(v+eps); shift = (b-m)*scale + be
__global__ __launch_bounds__(512) void params_kernel(
    const float* __restrict__ b0, const float* __restrict__ g0, const float* __restrict__ be0,
    const float* __restrict__ m0, const float* __restrict__ v0,
    const float* __restrict__ b1, const float* __restrict__ g1, const float* __restrict__ be1,
    const float* __restrict__ m1, const float* __restrict__ v1,
    float* __restrict__ sc0, float* __restrict__ sh0,
    float* __restrict__ sc1, float* __restrict__ sh1) {
  int t = threadIdx.x;
  if (t < 512) {
    float s = g0[t] / sqrtf(v0[t] + 1e-3f);
    sc0[t] = s;
    sh0[t] = (b0[t] - m0[t]) * s + be0[t];
  }
  if (t < 256) {
    float s = g1[t] / sqrtf(v1[t] + 1e-3f);
    sc1[t] = s;
    sh1[t] = (b1[t] - m1[t]) * s + be1[t];
  }
}

// ---------------- tiled transpose + f32->bf16 cast.
// in: [R][cols] f32 (batch stride ibs). out[(c)][r] bf16 with row stride ldo (batch stride obs).
__global__ __launch_bounds__(256) void transpose_cast_kernel(
    const float* __restrict__ in, unsigned short* __restrict__ out,
    int cols, int ldo, long ibs, long obs, int tilesPerRow) {
  __shared__ float tile[64][65];
  in += (size_t)blockIdx.y * ibs;
  out += (size_t)blockIdx.y * obs;
  const int tr = (blockIdx.x / tilesPerRow) * 64;
  const int tc = (blockIdx.x % tilesPerRow) * 64;
  const int lx = threadIdx.x & 63, ly = threadIdx.x >> 6;
#pragma unroll
  for (int i = ly; i < 64; i += 4)
    tile[i][lx] = in[(size_t)(tr + i) * cols + tc + lx];
  __syncthreads();
#pragma unroll
  for (int i = ly; i < 64; i += 4)
    out[(size_t)(tc + i) * ldo + tr + lx] = f2b(tile[lx][i]);
}

// ---------------- 3-NN: one thread per query point, full scan over S in LDS.
// Arithmetic mirrors the reference: sq = (|q|^2 + |s|^2) - 2*dot, fma-chain dot.
__global__ __launch_bounds__(256) void knn_kernel(
    const float* __restrict__ xyz1, const float* __restrict__ xyz2,
    int* __restrict__ oidx, float* __restrict__ ow) {
  __shared__ float sx[SPTS], sy[SPTS], sz[SPTS], sb[SPTS];
  const int batch = blockIdx.x >> 5;           // 32 blocks per batch
  const int nbase = (blockIdx.x & 31) << 8;    // *256
  const float* xb = xyz2 + (size_t)batch * 3 * SPTS;
  for (int i = threadIdx.x; i < SPTS; i += 256) {
    float a = xb[i], b = xb[SPTS + i], c = xb[2 * SPTS + i];
    sx[i] = a; sy[i] = b; sz[i] = c;
    sb[i] = __fadd_rn(__fadd_rn(__fmul_rn(a, a), __fmul_rn(b, b)), __fmul_rn(c, c));
  }
  __syncthreads();
  const int n = nbase + threadIdx.x;
  const float* q = xyz1 + (size_t)batch * 3 * NPTS;
  const float x = q[n], y = q[NPTS + n], z = q[2 * NPTS + n];
  const float qa = __fadd_rn(__fadd_rn(__fmul_rn(x, x), __fmul_rn(y, y)), __fmul_rn(z, z));
  float d0 = 3.4e38f, d1 = 3.4e38f, d2 = 3.4e38f;
  int i0 = 0, i1 = 0, i2 = 0;
#pragma unroll 4
  for (int s = 0; s < SPTS; ++s) {
    float dot = __builtin_fmaf(sz[s], z, __builtin_fmaf(sy[s], y, __fmul_rn(sx[s], x)));
    float sq = __fsub_rn(__fadd_rn(qa, sb[s]), __fmul_rn(2.0f, dot));
    if (sq < d2) {
      if (sq < d1) {
        d2 = d1; i2 = i1;
        if (sq < d0) { d1 = d0; i1 = i0; d0 = sq; i0 = s; }
        else { d1 = sq; i1 = s; }
      } else { d2 = sq; i2 = s; }
    }
  }
  float w0 = 1.0f / fmaxf(d0, 1e-10f);
  float w1 = 1.0f / fmaxf(d1, 1e-10f);
  float w2 = 1.0f / fmaxf(d2, 1e-10f);
  float sum = __fadd_rn(__fadd_rn(w0, w1), w2);
  const int p = batch * NPTS + n;
  oidx[3 * p + 0] = i0; oidx[3 * p + 1] = i1; oidx[3 * p + 2] = i2;
  ow[3 * p + 0] = w0 / sum; ow[3 * p + 1] = w1 / sum; ow[3 * p + 2] = w2 / sum;
}

// ---------------- interpolation: one wave per point; gathers 3 contiguous bf16 rows.
__global__ __launch_bounds__(256) void interp_kernel(
    const unsigned short* __restrict__ p2t, const int* __restrict__ oidx,
    const float* __restrict__ ow, unsigned short* __restrict__ A) {
  const int lane = threadIdx.x & 63;
  const int p = blockIdx.x * 4 + (threadIdx.x >> 6);
  const int b = p >> 13;
  float a0 = 0.f, a1 = 0.f, a2 = 0.f, a3 = 0.f;
#pragma unroll
  for (int k = 0; k < 3; ++k) {
    const int id = oidx[3 * p + k];
    const float w = ow[3 * p + k];
    const unsigned short* row = p2t + ((size_t)b * SPTS + id) * DF + lane * 4;
    u32x2 v = *reinterpret_cast<const u32x2*>(row);
    a0 = __builtin_fmaf(w, b2f((unsigned short)(v.x & 0xffff)), a0);
    a1 = __builtin_fmaf(w, b2f((unsigned short)(v.x >> 16)), a1);
    a2 = __builtin_fmaf(w, b2f((unsigned short)(v.y & 0xffff)), a2);
    a3 = __builtin_fmaf(w, b2f((unsigned short)(v.y >> 16)), a3);
  }
  u32x2 o;
  o.x = (unsigned)f2b(a0) | ((unsigned)f2b(a1) << 16);
  o.y = (unsigned)f2b(a2) | ((unsigned)f2b(a3) << 16);
  *reinterpret_cast<u32x2*>(A + (size_t)p * CIN + DF + lane * 4) = o;
}

// ---------------- bf16 MFMA GEMM: C[M,Nout] = A[M,512] * BT[Nout,512]^T
// 128x128 tile, BK=64, 4 waves (2x2), 16x16x32 MFMA, XOR-swizzled LDS.
// EPI 0: H = bf16(relu(c*scale+shift)), row-major [M][512]
// EPI 1: out f32 [B][256][N]: out[(row>>13)*256+col][row&8191]
template <int EPI>
__global__ __launch_bounds__(256) void gemm_kernel(
    const unsigned short* __restrict__ Abuf, const unsigned short* __restrict__ BT,
    const float* __restrict__ scale, const float* __restrict__ shift,
    void* __restrict__ outp, int gridN) {
  __shared__ unsigned short lA[128 * 64], lB[128 * 64];
  const int bn = blockIdx.x % gridN, bm = blockIdx.x / gridN;
  const int t = threadIdx.x;
  const int lane = t & 63, wave = t >> 6;
  const int wm = wave >> 1, wn = wave & 1;
  f32x4 acc[4][4] = {};
  const size_t arow0 = (size_t)bm * 128;
  const size_t brow0 = (size_t)bn * 128;
  for (int kb = 0; kb < 8; ++kb) {
    const int kbase = kb * 64;
#pragma unroll
    for (int j = 0; j < 4; ++j) {
      int chunk = t + 256 * j;  // 1024 16B-chunks per tile
      int row = chunk >> 3, k16 = chunk & 7;
      u32x4 va = *reinterpret_cast<const u32x4*>(Abuf + (arow0 + row) * 512 + kbase + k16 * 8);
      u32x4 vb = *reinterpret_cast<const u32x4*>(BT + (brow0 + row) * 512 + kbase + k16 * 8);
      int sidx = row * 8 + (k16 ^ (row & 7));
      reinterpret_cast<u32x4*>(lA)[sidx] = va;
      reinterpret_cast<u32x4*>(lB)[sidx] = vb;
    }
    __syncthreads();
#pragma unroll
    for (int kk = 0; kk < 2; ++kk) {
      bf16x8 af[4], bf[4];
      const int c16 = kk * 4 + (lane >> 4);
#pragma unroll
      for (int mi = 0; mi < 4; ++mi) {
        int row = wm * 64 + mi * 16 + (lane & 15);
        af[mi] = __builtin_bit_cast(bf16x8, reinterpret_cast<const u32x4*>(lA)[row * 8 + (c16 ^ (row & 7))]);
      }
#pragma unroll
      for (int ni = 0; ni < 4; ++ni) {
        int row = wn * 64 + ni * 16 + (lane & 15);
        bf[ni] = __builtin_bit_cast(bf16x8, reinterpret_cast<const u32x4*>(lB)[row * 8 + (c16 ^ (row & 7))]);
      }
#pragma unroll
      for (int mi = 0; mi < 4; ++mi)
#pragma unroll
        for (int ni = 0; ni < 4; ++ni)
          acc[mi][ni] = __builtin_amdgcn_mfma_f32_16x16x32_bf16(af[mi], bf[ni], acc[mi][ni], 0, 0, 0);
    }
    __syncthreads();
  }
  const int colb = bn * 128 + wn * 64;
  const int rowb = bm * 128 + wm * 64;
#pragma unroll
  for (int ni = 0; ni < 4; ++ni) {
    const int col = colb + ni * 16 + (lane & 15);
    const float sc = scale[col], sh = shift[col];
#pragma unroll
    for (int mi = 0; mi < 4; ++mi) {
      const int r0 = rowb + mi * 16 + ((lane >> 4) * 4);
#pragma unroll
      for (int j = 0; j < 4; ++j) {
        float v = fmaxf(__builtin_fmaf(acc[mi][ni][j], sc, sh), 0.0f);
        if (EPI == 0) {
          ((unsigned short*)outp)[(size_t)(r0 + j) * 512 + col] = f2b(v);
        } else {
          const int row = r0 + j;
          ((float*)outp)[(((size_t)(row >> 13) * 256 + col) << 13) | (size_t)(row & 8191)] = v;
        }
      }
    }
  }
}

extern "C" void kernel_launch(void* const* d_in, const int* in_sizes, int n_in,
                              void* d_out, int out_size, void* d_ws, size_t ws_size,
                              hipStream_t stream) {
  const float* xyz1 = (const float*)d_in[0];
  const float* xyz2 = (const float*)d_in[1];
  const float* points1 = (const float*)d_in[2];
  const float* points2 = (const float*)d_in[3];
  const float* w0 = (const float*)d_in[4];
  const float* b0 = (const float*)d_in[5];
  const float* g0 = (const float*)d_in[6];
  const float* be0 = (const float*)d_in[7];
  const float* m0 = (const float*)d_in[8];
  const float* v0 = (const float*)d_in[9];
  const float* w1 = (const float*)d_in[10];
  const float* b1 = (const float*)d_in[11];
  const float* g1 = (const float*)d_in[12];
  const float* be1 = (const float*)d_in[13];
  const float* m1 = (const float*)d_in[14];
  const float* v1 = (const float*)d_in[15];

  char* ws = (char*)d_ws;
  size_t off = 0;
  auto alloc = [&](size_t bytes) {
    void* p = ws + off;
    off += (bytes + 255) & ~(size_t)255;
    return p;
  };
  unsigned short* Abuf = (unsigned short*)alloc((size_t)MTOT * CIN * 2);   // 32 MB
  unsigned short* Hbuf = (unsigned short*)alloc((size_t)MTOT * 512 * 2);   // 32 MB
  unsigned short* W0T  = (unsigned short*)alloc((size_t)512 * 512 * 2);
  unsigned short* W1T  = (unsigned short*)alloc((size_t)256 * 512 * 2);
  unsigned short* P2T  = (unsigned short*)alloc((size_t)NB * SPTS * DF * 2);
  int*   oidx = (int*)alloc((size_t)MTOT * 3 * 4);
  float* ow   = (float*)alloc((size_t)MTOT * 3 * 4);
  float* sc0 = (float*)alloc(512 * 4);
  float* sh0 = (float*)alloc(512 * 4);
  float* sc1 = (float*)alloc(256 * 4);
  float* sh1 = (float*)alloc(256 * 4);
  (void)ws_size; (void)in_sizes; (void)n_in; (void)out_size;

  params_kernel<<<1, 512, 0, stream>>>(b0, g0, be0, m0, v0, b1, g1, be1, m1, v1,
                                       sc0, sh0, sc1, sh1);
  // w0 [512][512] -> W0T [512][512]
  transpose_cast_kernel<<<dim3(64, 1), 256, 0, stream>>>(w0, W0T, 512, 512, 0, 0, 8);
  // w1 [512][256] -> W1T [256][512]
  transpose_cast_kernel<<<dim3(32, 1), 256, 0, stream>>>(w1, W1T, 256, 512, 0, 0, 4);
  // points1 [B][256][8192] -> A[:, 0:256] (row stride 512)
  transpose_cast_kernel<<<dim3(512, NB), 256, 0, stream>>>(
      points1, Abuf, NPTS, CIN, (long)DF * NPTS, (long)NPTS * CIN, NPTS / 64);
  // points2 [B][256][2048] -> P2T [B][2048][256]
  transpose_cast_kernel<<<dim3(128, NB), 256, 0, stream>>>(
      points2, P2T, SPTS, DF, (long)DF * SPTS, (long)SPTS * DF, SPTS / 64);
  knn_kernel<<<128, 256, 0, stream>>>(xyz1, xyz2, oidx, ow);
  interp_kernel<<<MTOT / 4, 256, 0, stream>>>(P2T, oidx, ow, Abuf);
  gemm_kernel<0><<<dim3(256 * 4), 256, 0, stream>>>(Abuf, W0T, sc0, sh0, Hbuf, 4);
  gemm_kernel<1><<<dim3(256 * 2), 256, 0, stream>>>(Hbuf, W1T, sc1, sh1, d_out, 2);
}

// Round 2
// 130.292 us; speedup vs baseline: 2.0774x; 2.0774x over previous
//
#include <hip/hip_runtime.h>
#include <cstdint>
#include <cstddef>

typedef __attribute__((ext_vector_type(4))) float f32x4;
typedef __bf16 bf16x8 __attribute__((ext_vector_type(8)));
typedef __attribute__((ext_vector_type(4))) unsigned int u32x4;
typedef __attribute__((ext_vector_type(2))) unsigned int u32x2;

#define DEVI __device__ __forceinline__

static constexpr int NB = 4;      // batches
static constexpr int NPTS = 8192; // N query points
static constexpr int SPTS = 2048; // S source points
static constexpr int DF = 256;    // feature dim of points1/points2
static constexpr int CIN = 512;   // concat width = 2*DF = K of GEMM1
static constexpr int MTOT = NB * NPTS; // 32768 rows

DEVI unsigned short f2b(float f) {
  union { float f; unsigned u; } v; v.f = f;
  unsigned r = v.u + 0x7FFFu + ((v.u >> 16) & 1u);
  return (unsigned short)(r >> 16);
}
DEVI float b2f(unsigned short h) {
  union { unsigned u; float f; } v; v.u = ((unsigned)h) << 16;
  return v.f;
}

// ---------------- BN param folding: scale = g*rsqrt(v+eps); shift = (b-m)*scale + be
__global__ __launch_bounds__(512) void params_kernel(
    const float* __restrict__ b0, const float* __restrict__ g0, const float* __restrict__ be0,
    const float* __restrict__ m0, const float* __restrict__ v0,
    const float* __restrict__ b1, const float* __restrict__ g1, const float* __restrict__ be1,
    const float* __restrict__ m1, const float* __restrict__ v1,
    float* __restrict__ sc0, float* __restrict__ sh0,
    float* __restrict__ sc1, float* __restrict__ sh1) {
  int t = threadIdx.x;
  if (t < 512) {
    float s = g0[t] / sqrtf(v0[t] + 1e-3f);
    sc0[t] = s;
    sh0[t] = (b0[t] - m0[t]) * s + be0[t];
  }
  if (t < 256) {
    float s = g1[t] / sqrtf(v1[t] + 1e-3f);
    sc1[t] = s;
    sh1[t] = (b1[t] - m1[t]) * s + be1[t];
  }
}

// ---------------- tiled transpose + f32->bf16 cast.
// in: [R][cols] f32 (batch stride ibs). out[(c)][r] bf16 with row stride ldo (batch stride obs).
__global__ __launch_bounds__(256) void transpose_cast_kernel(
    const float* __restrict__ in, unsigned short* __restrict__ out,
    int cols, int ldo, long ibs, long obs, int tilesPerRow) {
  __shared__ float tile[64][65];
  in += (size_t)blockIdx.y * ibs;
  out += (size_t)blockIdx.y * obs;
  const int tr = (blockIdx.x / tilesPerRow) * 64;
  const int tc = (blockIdx.x % tilesPerRow) * 64;
  const int lx = threadIdx.x & 63, ly = threadIdx.x >> 6;
#pragma unroll
  for (int i = ly; i < 64; i += 4)
    tile[i][lx] = in[(size_t)(tr + i) * cols + tc + lx];
  __syncthreads();
#pragma unroll
  for (int i = ly; i < 64; i += 4)
    out[(size_t)(tc + i) * ldo + tr + lx] = f2b(tile[lx][i]);
}

// ---------------- 3-NN, wave-parallel over S.
// Block = 512 threads = 8 waves, owns 64 query points (lane = query).
// Wave w scans contiguous chunk [w*256, (w+1)*256) keeping a private top-3;
// all lanes of a wave read the same LDS source entry (broadcast, conflict-free).
// Wave 0 merges the 7 partials in ascending chunk order with strict '<'
// — exactly reproduces the serial lowest-index-on-tie semantics.
// Per-pair arithmetic is byte-identical to the reference:
//   sq = (|q|^2 + |s|^2) - 2*dot, fma-chain dot.
__global__ __launch_bounds__(512) void knn_kernel(
    const float* __restrict__ xyz1, const float* __restrict__ xyz2,
    int* __restrict__ oidx, float* __restrict__ ow) {
  __shared__ float sx[SPTS], sy[SPTS], sz[SPTS], sb[SPTS];
  __shared__ float md[7][64][3];
  __shared__ int   mi[7][64][3];
  const int batch = blockIdx.x >> 7;           // 128 blocks per batch
  const int nbase = (blockIdx.x & 127) << 6;   // *64
  const float* xb = xyz2 + (size_t)batch * 3 * SPTS;
  for (int i = threadIdx.x; i < SPTS; i += 512) {
    float a = xb[i], b = xb[SPTS + i], c = xb[2 * SPTS + i];
    sx[i] = a; sy[i] = b; sz[i] = c;
    sb[i] = __fadd_rn(__fadd_rn(__fmul_rn(a, a), __fmul_rn(b, b)), __fmul_rn(c, c));
  }
  __syncthreads();
  const int lane = threadIdx.x & 63, wave = threadIdx.x >> 6;
  const int n = nbase + lane;
  const float* q = xyz1 + (size_t)batch * 3 * NPTS;
  const float x = q[n], y = q[NPTS + n], z = q[2 * NPTS + n];
  const float qa = __fadd_rn(__fadd_rn(__fmul_rn(x, x), __fmul_rn(y, y)), __fmul_rn(z, z));
  float d0 = 3.4e38f, d1 = 3.4e38f, d2 = 3.4e38f;
  int i0 = 0, i1 = 0, i2 = 0;
  const int s0 = wave << 8;
#pragma unroll 4
  for (int s = s0; s < s0 + 256; ++s) {
    float dot = __builtin_fmaf(sz[s], z, __builtin_fmaf(sy[s], y, __fmul_rn(sx[s], x)));
    float sq = __fsub_rn(__fadd_rn(qa, sb[s]), __fmul_rn(2.0f, dot));
    if (sq < d2) {
      if (sq < d1) {
        d2 = d1; i2 = i1;
        if (sq < d0) { d1 = d0; i1 = i0; d0 = sq; i0 = s; }
        else { d1 = sq; i1 = s; }
      } else { d2 = sq; i2 = s; }
    }
  }
  if (wave != 0) {
    md[wave - 1][lane][0] = d0; mi[wave - 1][lane][0] = i0;
    md[wave - 1][lane][1] = d1; mi[wave - 1][lane][1] = i1;
    md[wave - 1][lane][2] = d2; mi[wave - 1][lane][2] = i2;
  }
  __syncthreads();
  if (wave != 0) return;
#pragma unroll
  for (int w = 0; w < 7; ++w) {
#pragma unroll
    for (int j = 0; j < 3; ++j) {
      float sq = md[w][lane][j];
      int si = mi[w][lane][j];
      if (sq < d2) {
        if (sq < d1) {
          d2 = d1; i2 = i1;
          if (sq < d0) { d1 = d0; i1 = i0; d0 = sq; i0 = si; }
          else { d1 = sq; i1 = si; }
        } else { d2 = sq; i2 = si; }
      }
    }
  }
  float w0 = 1.0f / fmaxf(d0, 1e-10f);
  float w1 = 1.0f / fmaxf(d1, 1e-10f);
  float w2 = 1.0f / fmaxf(d2, 1e-10f);
  float sum = __fadd_rn(__fadd_rn(w0, w1), w2);
  const int p = batch * NPTS + n;
  oidx[3 * p + 0] = i0; oidx[3 * p + 1] = i1; oidx[3 * p + 2] = i2;
  ow[3 * p + 0] = w0 / sum; ow[3 * p + 1] = w1 / sum; ow[3 * p + 2] = w2 / sum;
}

// ---------------- interpolation: one wave per point; gathers 3 contiguous bf16 rows.
__global__ __launch_bounds__(256) void interp_kernel(
    const unsigned short* __restrict__ p2t, const int* __restrict__ oidx,
    const float* __restrict__ ow, unsigned short* __restrict__ A) {
  const int lane = threadIdx.x & 63;
  const int p = blockIdx.x * 4 + (threadIdx.x >> 6);
  const int b = p >> 13;
  float a0 = 0.f, a1 = 0.f, a2 = 0.f, a3 = 0.f;
#pragma unroll
  for (int k = 0; k < 3; ++k) {
    const int id = oidx[3 * p + k];
    const float w = ow[3 * p + k];
    const unsigned short* row = p2t + ((size_t)b * SPTS + id) * DF + lane * 4;
    u32x2 v = *reinterpret_cast<const u32x2*>(row);
    a0 = __builtin_fmaf(w, b2f((unsigned short)(v.x & 0xffff)), a0);
    a1 = __builtin_fmaf(w, b2f((unsigned short)(v.x >> 16)), a1);
    a2 = __builtin_fmaf(w, b2f((unsigned short)(v.y & 0xffff)), a2);
    a3 = __builtin_fmaf(w, b2f((unsigned short)(v.y >> 16)), a3);
  }
  u32x2 o;
  o.x = (unsigned)f2b(a0) | ((unsigned)f2b(a1) << 16);
  o.y = (unsigned)f2b(a2) | ((unsigned)f2b(a3) << 16);
  *reinterpret_cast<u32x2*>(A + (size_t)p * CIN + DF + lane * 4) = o;
}

// ---------------- bf16 MFMA GEMM: C[M,Nout] = A[M,512] * BT[Nout,512]^T
// 128x128 tile, BK=64, 4 waves (2x2), 16x16x32 MFMA, XOR-swizzled LDS.
// EPI 0: H = bf16(relu(c*scale+shift)), row-major [M][512]
// EPI 1: out f32 [B][256][N]: out[(row>>13)*256+col][row&8191]
template <int EPI>
__global__ __launch_bounds__(256) void gemm_kernel(
    const unsigned short* __restrict__ Abuf, const unsigned short* __restrict__ BT,
    const float* __restrict__ scale, const float* __restrict__ shift,
    void* __restrict__ outp, int gridN) {
  __shared__ unsigned short lA[128 * 64], lB[128 * 64];
  const int bn = blockIdx.x % gridN, bm = blockIdx.x / gridN;
  const int t = threadIdx.x;
  const int lane = t & 63, wave = t >> 6;
  const int wm = wave >> 1, wn = wave & 1;
  f32x4 acc[4][4] = {};
  const size_t arow0 = (size_t)bm * 128;
  const size_t brow0 = (size_t)bn * 128;
  for (int kb = 0; kb < 8; ++kb) {
    const int kbase = kb * 64;
#pragma unroll
    for (int j = 0; j < 4; ++j) {
      int chunk = t + 256 * j;  // 1024 16B-chunks per tile
      int row = chunk >> 3, k16 = chunk & 7;
      u32x4 va = *reinterpret_cast<const u32x4*>(Abuf + (arow0 + row) * 512 + kbase + k16 * 8);
      u32x4 vb = *reinterpret_cast<const u32x4*>(BT + (brow0 + row) * 512 + kbase + k16 * 8);
      int sidx = row * 8 + (k16 ^ (row & 7));
      reinterpret_cast<u32x4*>(lA)[sidx] = va;
      reinterpret_cast<u32x4*>(lB)[sidx] = vb;
    }
    __syncthreads();
#pragma unroll
    for (int kk = 0; kk < 2; ++kk) {
      bf16x8 af[4], bf[4];
      const int c16 = kk * 4 + (lane >> 4);
#pragma unroll
      for (int mi = 0; mi < 4; ++mi) {
        int row = wm * 64 + mi * 16 + (lane & 15);
        af[mi] = __builtin_bit_cast(bf16x8, reinterpret_cast<const u32x4*>(lA)[row * 8 + (c16 ^ (row & 7))]);
      }
#pragma unroll
      for (int ni = 0; ni < 4; ++ni) {
        int row = wn * 64 + ni * 16 + (lane & 15);
        bf[ni] = __builtin_bit_cast(bf16x8, reinterpret_cast<const u32x4*>(lB)[row * 8 + (c16 ^ (row & 7))]);
      }
#pragma unroll
      for (int mi = 0; mi < 4; ++mi)
#pragma unroll
        for (int ni = 0; ni < 4; ++ni)
          acc[mi][ni] = __builtin_amdgcn_mfma_f32_16x16x32_bf16(af[mi], bf[ni], acc[mi][ni], 0, 0, 0);
    }
    __syncthreads();
  }
  const int colb = bn * 128 + wn * 64;
  const int rowb = bm * 128 + wm * 64;
#pragma unroll
  for (int ni = 0; ni < 4; ++ni) {
    const int col = colb + ni * 16 + (lane & 15);
    const float sc = scale[col], sh = shift[col];
#pragma unroll
    for (int mi = 0; mi < 4; ++mi) {
      const int r0 = rowb + mi * 16 + ((lane >> 4) * 4);
#pragma unroll
      for (int j = 0; j < 4; ++j) {
        float v = fmaxf(__builtin_fmaf(acc[mi][ni][j], sc, sh), 0.0f);
        if (EPI == 0) {
          ((unsigned short*)outp)[(size_t)(r0 + j) * 512 + col] = f2b(v);
        } else {
          const int row = r0 + j;
          ((float*)outp)[(((size_t)(row >> 13) * 256 + col) << 13) | (size_t)(row & 8191)] = v;
        }
      }
    }
  }
}

extern "C" void kernel_launch(void* const* d_in, const int* in_sizes, int n_in,
                              void* d_out, int out_size, void* d_ws, size_t ws_size,
                              hipStream_t stream) {
  const float* xyz1 = (const float*)d_in[0];
  const float* xyz2 = (const float*)d_in[1];
  const float* points1 = (const float*)d_in[2];
  const float* points2 = (const float*)d_in[3];
  const float* w0 = (const float*)d_in[4];
  const float* b0 = (const float*)d_in[5];
  const float* g0 = (const float*)d_in[6];
  const float* be0 = (const float*)d_in[7];
  const float* m0 = (const float*)d_in[8];
  const float* v0 = (const float*)d_in[9];
  const float* w1 = (const float*)d_in[10];
  const float* b1 = (const float*)d_in[11];
  const float* g1 = (const float*)d_in[12];
  const float* be1 = (const float*)d_in[13];
  const float* m1 = (const float*)d_in[14];
  const float* v1 = (const float*)d_in[15];

  char* ws = (char*)d_ws;
  size_t off = 0;
  auto alloc = [&](size_t bytes) {
    void* p = ws + off;
    off += (bytes + 255) & ~(size_t)255;
    return p;
  };
  unsigned short* Abuf = (unsigned short*)alloc((size_t)MTOT * CIN * 2);   // 32 MB
  unsigned short* Hbuf = (unsigned short*)alloc((size_t)MTOT * 512 * 2);   // 32 MB
  unsigned short* W0T  = (unsigned short*)alloc((size_t)512 * 512 * 2);
  unsigned short* W1T  = (unsigned short*)alloc((size_t)256 * 512 * 2);
  unsigned short* P2T  = (unsigned short*)alloc((size_t)NB * SPTS * DF * 2);
  int*   oidx = (int*)alloc((size_t)MTOT * 3 * 4);
  float* ow   = (float*)alloc((size_t)MTOT * 3 * 4);
  float* sc0 = (float*)alloc(512 * 4);
  float* sh0 = (float*)alloc(512 * 4);
  float* sc1 = (float*)alloc(256 * 4);
  float* sh1 = (float*)alloc(256 * 4);
  (void)ws_size; (void)in_sizes; (void)n_in; (void)out_size;

  params_kernel<<<1, 512, 0, stream>>>(b0, g0, be0, m0, v0, b1, g1, be1, m1, v1,
                                       sc0, sh0, sc1, sh1);
  // w0 [512][512] -> W0T [512][512]
  transpose_cast_kernel<<<dim3(64, 1), 256, 0, stream>>>(w0, W0T, 512, 512, 0, 0, 8);
  // w1 [512][256] -> W1T [256][512]
  transpose_cast_kernel<<<dim3(32, 1), 256, 0, stream>>>(w1, W1T, 256, 512, 0, 0, 4);
  // points1 [B][256][8192] -> A[:, 0:256] (row stride 512)
  transpose_cast_kernel<<<dim3(512, NB), 256, 0, stream>>>(
      points1, Abuf, NPTS, CIN, (long)DF * NPTS, (long)NPTS * CIN, NPTS / 64);
  // points2 [B][256][2048] -> P2T [B][2048][256]
  transpose_cast_kernel<<<dim3(128, NB), 256, 0, stream>>>(
      points2, P2T, SPTS, DF, (long)DF * SPTS, (long)SPTS * DF, SPTS / 64);
  knn_kernel<<<512, 512, 0, stream>>>(xyz1, xyz2, oidx, ow);
  interp_kernel<<<MTOT / 4, 256, 0, stream>>>(P2T, oidx, ow, Abuf);
  gemm_kernel<0><<<dim3(256 * 4), 256, 0, stream>>>(Abuf, W0T, sc0, sh0, Hbuf, 4);
  gemm_kernel<1><<<dim3(256 * 2), 256, 0, stream>>>(Hbuf, W1T, sc1, sh1, d_out, 2);
}

// Round 3
// 117.707 us; speedup vs baseline: 2.2995x; 1.1069x over previous
//
#include <hip/hip_runtime.h>
#include <cstdint>
#include <cstddef>

typedef __attribute__((ext_vector_type(4))) float f32x4;
typedef __bf16 bf16x8 __attribute__((ext_vector_type(8)));
typedef __attribute__((ext_vector_type(4))) unsigned int u32x4;
typedef __attribute__((ext_vector_type(2))) unsigned int u32x2;

#define DEVI __device__ __forceinline__

static constexpr int NB = 4;      // batches
static constexpr int NPTS = 8192; // N query points
static constexpr int SPTS = 2048; // S source points
static constexpr int DF = 256;    // feature dim of points1/points2
static constexpr int CIN = 512;   // concat width = 2*DF = K of GEMM1
static constexpr int MTOT = NB * NPTS; // 32768 rows

DEVI unsigned short f2b(float f) {
  union { float f; unsigned u; } v; v.f = f;
  unsigned r = v.u + 0x7FFFu + ((v.u >> 16) & 1u);
  return (unsigned short)(r >> 16);
}
DEVI float b2f(unsigned short h) {
  union { unsigned u; float f; } v; v.u = ((unsigned)h) << 16;
  return v.f;
}

typedef const __attribute__((address_space(1))) unsigned int* gas_t;
typedef __attribute__((address_space(3))) unsigned int* las_t;
DEVI void gload16(const void* g, void* l) {
  // async global->LDS, 16B per lane; LDS dest = uniform base + lane*16
  __builtin_amdgcn_global_load_lds((gas_t)g, (las_t)l, 16, 0, 0);
}

// ---------------- BN param folding: scale = g*rsqrt(v+eps); shift = (b-m)*scale + be
__global__ __launch_bounds__(512) void params_kernel(
    const float* __restrict__ b0, const float* __restrict__ g0, const float* __restrict__ be0,
    const float* __restrict__ m0, const float* __restrict__ v0,
    const float* __restrict__ b1, const float* __restrict__ g1, const float* __restrict__ be1,
    const float* __restrict__ m1, const float* __restrict__ v1,
    float* __restrict__ sc0, float* __restrict__ sh0,
    float* __restrict__ sc1, float* __restrict__ sh1) {
  int t = threadIdx.x;
  if (t < 512) {
    float s = g0[t] / sqrtf(v0[t] + 1e-3f);
    sc0[t] = s;
    sh0[t] = (b0[t] - m0[t]) * s + be0[t];
  }
  if (t < 256) {
    float s = g1[t] / sqrtf(v1[t] + 1e-3f);
    sc1[t] = s;
    sh1[t] = (b1[t] - m1[t]) * s + be1[t];
  }
}

// ---------------- tiled transpose + f32->bf16 cast.
__global__ __launch_bounds__(256) void transpose_cast_kernel(
    const float* __restrict__ in, unsigned short* __restrict__ out,
    int cols, int ldo, long ibs, long obs, int tilesPerRow) {
  __shared__ float tile[64][65];
  in += (size_t)blockIdx.y * ibs;
  out += (size_t)blockIdx.y * obs;
  const int tr = (blockIdx.x / tilesPerRow) * 64;
  const int tc = (blockIdx.x % tilesPerRow) * 64;
  const int lx = threadIdx.x & 63, ly = threadIdx.x >> 6;
#pragma unroll
  for (int i = ly; i < 64; i += 4)
    tile[i][lx] = in[(size_t)(tr + i) * cols + tc + lx];
  __syncthreads();
#pragma unroll
  for (int i = ly; i < 64; i += 4)
    out[(size_t)(tc + i) * ldo + tr + lx] = f2b(tile[lx][i]);
}

// ---------------- 3-NN, wave-parallel over S, branchless top-3.
// Block = 512 threads = 8 waves, owns 64 query points (lane = query).
// Wave w scans contiguous chunk [w*256,(w+1)*256); sources packed {x,y,z,|s|^2}
// as float4 in LDS -> one uniform ds_read_b128 broadcast per source.
// Branchless sorted insert uses the same predicates (strict <, old d values)
// as the serial reference scan -> identical selection & tie-break.
__global__ __launch_bounds__(512) void knn_kernel(
    const float* __restrict__ xyz1, const float* __restrict__ xyz2,
    int* __restrict__ oidx, float* __restrict__ ow) {
  __shared__ f32x4 sp[SPTS];
  __shared__ float md[7][64][3];
  __shared__ int   mi[7][64][3];
  const int batch = blockIdx.x >> 7;           // 128 blocks per batch
  const int nbase = (blockIdx.x & 127) << 6;   // *64
  const float* xb = xyz2 + (size_t)batch * 3 * SPTS;
  for (int i = threadIdx.x; i < SPTS; i += 512) {
    float a = xb[i], b = xb[SPTS + i], c = xb[2 * SPTS + i];
    f32x4 v;
    v.x = a; v.y = b; v.z = c;
    v.w = __fadd_rn(__fadd_rn(__fmul_rn(a, a), __fmul_rn(b, b)), __fmul_rn(c, c));
    sp[i] = v;
  }
  __syncthreads();
  const int lane = threadIdx.x & 63, wave = threadIdx.x >> 6;
  const int n = nbase + lane;
  const float* q = xyz1 + (size_t)batch * 3 * NPTS;
  const float x = q[n], y = q[NPTS + n], z = q[2 * NPTS + n];
  const float qa = __fadd_rn(__fadd_rn(__fmul_rn(x, x), __fmul_rn(y, y)), __fmul_rn(z, z));
  float d0 = 3.4e38f, d1 = 3.4e38f, d2 = 3.4e38f;
  int i0 = 0, i1 = 0, i2 = 0;
  const int s0 = wave << 8;
#pragma unroll 8
  for (int s = s0; s < s0 + 256; ++s) {
    f32x4 v = sp[s];
    float dot = __builtin_fmaf(v.z, z, __builtin_fmaf(v.y, y, __fmul_rn(v.x, x)));
    // (qa+sb) - 2*dot: 2*dot is exact, so fma(-2,dot,t) == fsub(t, fmul(2,dot))
    float sq = __builtin_fmaf(-2.0f, dot, __fadd_rn(qa, v.w));
    const bool c0 = sq < d0, c1 = sq < d1, c2 = sq < d2;
    d2 = c1 ? d1 : (c2 ? sq : d2);
    i2 = c1 ? i1 : (c2 ? s : i2);
    d1 = c0 ? d0 : (c1 ? sq : d1);
    i1 = c0 ? i0 : (c1 ? s : i1);
    d0 = c0 ? sq : d0;
    i0 = c0 ? s : i0;
  }
  if (wave != 0) {
    md[wave - 1][lane][0] = d0; mi[wave - 1][lane][0] = i0;
    md[wave - 1][lane][1] = d1; mi[wave - 1][lane][1] = i1;
    md[wave - 1][lane][2] = d2; mi[wave - 1][lane][2] = i2;
  }
  __syncthreads();
  if (wave != 0) return;
#pragma unroll
  for (int w = 0; w < 7; ++w) {
#pragma unroll
    for (int j = 0; j < 3; ++j) {
      float sq = md[w][lane][j];
      int si = mi[w][lane][j];
      const bool c0 = sq < d0, c1 = sq < d1, c2 = sq < d2;
      d2 = c1 ? d1 : (c2 ? sq : d2);
      i2 = c1 ? i1 : (c2 ? si : i2);
      d1 = c0 ? d0 : (c1 ? sq : d1);
      i1 = c0 ? i0 : (c1 ? si : i1);
      d0 = c0 ? sq : d0;
      i0 = c0 ? si : i0;
    }
  }
  float w0 = 1.0f / fmaxf(d0, 1e-10f);
  float w1 = 1.0f / fmaxf(d1, 1e-10f);
  float w2 = 1.0f / fmaxf(d2, 1e-10f);
  float sum = __fadd_rn(__fadd_rn(w0, w1), w2);
  const int p = batch * NPTS + n;
  oidx[3 * p + 0] = i0; oidx[3 * p + 1] = i1; oidx[3 * p + 2] = i2;
  ow[3 * p + 0] = w0 / sum; ow[3 * p + 1] = w1 / sum; ow[3 * p + 2] = w2 / sum;
}

// ---------------- interpolation: one wave per point; gathers 3 contiguous bf16 rows.
__global__ __launch_bounds__(256) void interp_kernel(
    const unsigned short* __restrict__ p2t, const int* __restrict__ oidx,
    const float* __restrict__ ow, unsigned short* __restrict__ A) {
  const int lane = threadIdx.x & 63;
  const int p = blockIdx.x * 4 + (threadIdx.x >> 6);
  const int b = p >> 13;
  float a0 = 0.f, a1 = 0.f, a2 = 0.f, a3 = 0.f;
#pragma unroll
  for (int k = 0; k < 3; ++k) {
    const int id = oidx[3 * p + k];
    const float w = ow[3 * p + k];
    const unsigned short* row = p2t + ((size_t)b * SPTS + id) * DF + lane * 4;
    u32x2 v = *reinterpret_cast<const u32x2*>(row);
    a0 = __builtin_fmaf(w, b2f((unsigned short)(v.x & 0xffff)), a0);
    a1 = __builtin_fmaf(w, b2f((unsigned short)(v.x >> 16)), a1);
    a2 = __builtin_fmaf(w, b2f((unsigned short)(v.y & 0xffff)), a2);
    a3 = __builtin_fmaf(w, b2f((unsigned short)(v.y >> 16)), a3);
  }
  u32x2 o;
  o.x = (unsigned)f2b(a0) | ((unsigned)f2b(a1) << 16);
  o.y = (unsigned)f2b(a2) | ((unsigned)f2b(a3) << 16);
  *reinterpret_cast<u32x2*>(A + (size_t)p * CIN + DF + lane * 4) = o;
}

// ---------------- bf16 MFMA GEMM: C[M,Nout] = A[M,512] * BT[Nout,512]^T
// 128x128 tile, BK=64, 4 waves (2x2), 16x16x32 MFMA.
// global_load_lds (16B) with pre-swizzled global source + linear LDS dest +
// XOR-swizzled ds_read (rule #21 both-sides pattern). Double-buffered
// 2-phase pipeline: STAGE(next) issued before compute(cur), one drain+barrier
// per K-step. XCD-chunked block swizzle for A-panel L2 reuse.
// EPI 0: H = bf16(relu(c*scale+shift)), row-major [M][512]
// EPI 1: out f32 [B][256][N]: out[(row>>13)*256+col][row&8191]
template <int EPI>
__global__ __launch_bounds__(256) void gemm_kernel(
    const unsigned short* __restrict__ Abuf, const unsigned short* __restrict__ BT,
    const float* __restrict__ scale, const float* __restrict__ shift,
    void* __restrict__ outp, int gridN) {
  __shared__ u32x4 lsA[2][1024], lsB[2][1024];  // 2 x 16KB each
  // XCD-chunked swizzle (gridDim.x % 8 == 0): each XCD gets a contiguous chunk
  const int wg = (blockIdx.x & 7) * (gridDim.x >> 3) + (blockIdx.x >> 3);
  const int bn = wg % gridN, bm = wg / gridN;
  const int t = threadIdx.x;
  const int lane = t & 63, wave = t >> 6;
  const int wm = wave >> 1, wn = wave & 1;
  f32x4 acc[4][4] = {};
  const size_t arow0 = (size_t)bm * 128;
  const size_t brow0 = (size_t)bn * 128;

  // per-wave: 4 gload16 calls for A + 4 for B cover the 128x64 bf16 tile
  auto stage = [&](int buf, int kb) {
    const int kbase = kb * 64;
#pragma unroll
    for (int i = 0; i < 4; ++i) {
      const int c = wave * 256 + i * 64 + lane;     // chunk index 0..1023
      const int row = c >> 3;
      const int k16 = (c & 7) ^ (row & 7);          // inverse-swizzled source
      gload16(Abuf + (arow0 + row) * 512 + kbase + k16 * 8,
              &lsA[buf][wave * 256 + i * 64]);
      gload16(BT + (brow0 + row) * 512 + kbase + k16 * 8,
              &lsB[buf][wave * 256 + i * 64]);
    }
  };

  stage(0, 0);
  __syncthreads();  // compiler drains vmcnt before s_barrier
  int cur = 0;
  for (int kb = 0; kb < 8; ++kb) {
    if (kb < 7) stage(cur ^ 1, kb + 1);  // async prefetch overlaps compute
#pragma unroll
    for (int kk = 0; kk < 2; ++kk) {
      bf16x8 af[4], bf[4];
      const int c16 = kk * 4 + (lane >> 4);
#pragma unroll
      for (int mi = 0; mi < 4; ++mi) {
        int row = wm * 64 + mi * 16 + (lane & 15);
        af[mi] = __builtin_bit_cast(bf16x8, lsA[cur][row * 8 + (c16 ^ (row & 7))]);
      }
#pragma unroll
      for (int ni = 0; ni < 4; ++ni) {
        int row = wn * 64 + ni * 16 + (lane & 15);
        bf[ni] = __builtin_bit_cast(bf16x8, lsB[cur][row * 8 + (c16 ^ (row & 7))]);
      }
#pragma unroll
      for (int mi = 0; mi < 4; ++mi)
#pragma unroll
        for (int ni = 0; ni < 4; ++ni)
          acc[mi][ni] = __builtin_amdgcn_mfma_f32_16x16x32_bf16(af[mi], bf[ni], acc[mi][ni], 0, 0, 0);
    }
    __syncthreads();  // drains vmcnt(0) (next tile landed) + lgkmcnt
    cur ^= 1;
  }
  const int colb = bn * 128 + wn * 64;
  const int rowb = bm * 128 + wm * 64;
#pragma unroll
  for (int ni = 0; ni < 4; ++ni) {
    const int col = colb + ni * 16 + (lane & 15);
    const float sc = scale[col], sh = shift[col];
#pragma unroll
    for (int mi = 0; mi < 4; ++mi) {
      const int r0 = rowb + mi * 16 + ((lane >> 4) * 4);
#pragma unroll
      for (int j = 0; j < 4; ++j) {
        float v = fmaxf(__builtin_fmaf(acc[mi][ni][j], sc, sh), 0.0f);
        if (EPI == 0) {
          ((unsigned short*)outp)[(size_t)(r0 + j) * 512 + col] = f2b(v);
        } else {
          const int row = r0 + j;
          ((float*)outp)[(((size_t)(row >> 13) * 256 + col) << 13) | (size_t)(row & 8191)] = v;
        }
      }
    }
  }
}

extern "C" void kernel_launch(void* const* d_in, const int* in_sizes, int n_in,
                              void* d_out, int out_size, void* d_ws, size_t ws_size,
                              hipStream_t stream) {
  const float* xyz1 = (const float*)d_in[0];
  const float* xyz2 = (const float*)d_in[1];
  const float* points1 = (const float*)d_in[2];
  const float* points2 = (const float*)d_in[3];
  const float* w0 = (const float*)d_in[4];
  const float* b0 = (const float*)d_in[5];
  const float* g0 = (const float*)d_in[6];
  const float* be0 = (const float*)d_in[7];
  const float* m0 = (const float*)d_in[8];
  const float* v0 = (const float*)d_in[9];
  const float* w1 = (const float*)d_in[10];
  const float* b1 = (const float*)d_in[11];
  const float* g1 = (const float*)d_in[12];
  const float* be1 = (const float*)d_in[13];
  const float* m1 = (const float*)d_in[14];
  const float* v1 = (const float*)d_in[15];

  char* ws = (char*)d_ws;
  size_t off = 0;
  auto alloc = [&](size_t bytes) {
    void* p = ws + off;
    off += (bytes + 255) & ~(size_t)255;
    return p;
  };
  unsigned short* Abuf = (unsigned short*)alloc((size_t)MTOT * CIN * 2);   // 32 MB
  unsigned short* Hbuf = (unsigned short*)alloc((size_t)MTOT * 512 * 2);   // 32 MB
  unsigned short* W0T  = (unsigned short*)alloc((size_t)512 * 512 * 2);
  unsigned short* W1T  = (unsigned short*)alloc((size_t)256 * 512 * 2);
  unsigned short* P2T  = (unsigned short*)alloc((size_t)NB * SPTS * DF * 2);
  int*   oidx = (int*)alloc((size_t)MTOT * 3 * 4);
  float* ow   = (float*)alloc((size_t)MTOT * 3 * 4);
  float* sc0 = (float*)alloc(512 * 4);
  float* sh0 = (float*)alloc(512 * 4);
  float* sc1 = (float*)alloc(256 * 4);
  float* sh1 = (float*)alloc(256 * 4);
  (void)ws_size; (void)in_sizes; (void)n_in; (void)out_size;

  params_kernel<<<1, 512, 0, stream>>>(b0, g0, be0, m0, v0, b1, g1, be1, m1, v1,
                                       sc0, sh0, sc1, sh1);
  transpose_cast_kernel<<<dim3(64, 1), 256, 0, stream>>>(w0, W0T, 512, 512, 0, 0, 8);
  transpose_cast_kernel<<<dim3(32, 1), 256, 0, stream>>>(w1, W1T, 256, 512, 0, 0, 4);
  transpose_cast_kernel<<<dim3(512, NB), 256, 0, stream>>>(
      points1, Abuf, NPTS, CIN, (long)DF * NPTS, (long)NPTS * CIN, NPTS / 64);
  transpose_cast_kernel<<<dim3(128, NB), 256, 0, stream>>>(
      points2, P2T, SPTS, DF, (long)DF * SPTS, (long)SPTS * DF, SPTS / 64);
  knn_kernel<<<512, 512, 0, stream>>>(xyz1, xyz2, oidx, ow);
  interp_kernel<<<MTOT / 4, 256, 0, stream>>>(P2T, oidx, ow, Abuf);
  gemm_kernel<0><<<dim3(256 * 4), 256, 0, stream>>>(Abuf, W0T, sc0, sh0, Hbuf, 4);
  gemm_kernel<1><<<dim3(256 * 2), 256, 0, stream>>>(Hbuf, W1T, sc1, sh1, d_out, 2);
}